// Round 6
// baseline (50.875 us; speedup 1.0000x reference)
//
#include <hip/hip_runtime.h>
#include <math.h>

// Problem constants (match reference)
#define BB   8
#define HH   256
#define WW   256
#define CINN 128
#define WDIM 512
#define COUT 3

constexpr float LRELU_SLOPE = 0.2f;
constexpr float ACT_GAIN    = 1.4142135623730951f;   // sqrt(2)
constexpr float FC_SCALE    = 0.04419417382415922f;  // 1/sqrt(512)
constexpr float CONV_SCALE  = 0.08838834764831843f;  // 1/sqrt(128)

constexpr int PIX = HH * WW;                 // 65536 pixels per batch
constexpr int GRID_X = 256;                  // blocks per batch for kernel 2
constexpr int GROUPS_PER_BLK = 256 / 8;      // 32 groups of 8 lanes
constexpr int NGROUPS = GRID_X * GROUPS_PER_BLK;  // 8192 groups per batch
constexpr int ITERS = PIX / NGROUPS;         // 8 pixels per group

// ---------------------------------------------------------------------------
// Kernel 1: style FC + fold into coef[b][i][o].
// grid (B, 8): block owns batch b, channels cg*16..cg*16+15.
// block 256 = 16 channels x 16 k-slices of 32. LDS reduce.
// ---------------------------------------------------------------------------
__global__ __launch_bounds__(256)
void style_kernel(const float* __restrict__ w,
                  const float* __restrict__ fc_w,
                  const float* __restrict__ fc_b,
                  const float* __restrict__ conv_w,
                  float* __restrict__ coef) {
    __shared__ float wrow[WDIM];
    __shared__ float part[16][16];

    const int b  = blockIdx.x;
    const int c0 = blockIdx.y * 16;            // first channel of this block
    const int c  = threadIdx.x & 15;           // channel within group
    const int s  = threadIdx.x >> 4;           // k-slice 0..15

    // stage w[b,:] into LDS (coalesced, 2 per thread)
    wrow[threadIdx.x]       = w[b * WDIM + threadIdx.x];
    wrow[threadIdx.x + 256] = w[b * WDIM + threadIdx.x + 256];
    __syncthreads();

    const float* fcol = fc_w + (size_t)(s * 32) * CINN + (c0 + c);
    const float* wk   = wrow + s * 32;

    float acc = 0.f;
    #pragma unroll
    for (int k = 0; k < 32; ++k)
        acc = fmaf(wk[k], fcol[(size_t)k * CINN], acc);

    part[s][c] = acc;
    __syncthreads();

    if (threadIdx.x < 16) {                    // thread c finalizes channel c0+c
        float t = 0.f;
        #pragma unroll
        for (int r = 0; r < 16; ++r) t += part[r][threadIdx.x];
        const int i = c0 + threadIdx.x;
        t = t * FC_SCALE + fc_b[i];
        t = (t > 0.f ? t : LRELU_SLOPE * t) * (ACT_GAIN * CONV_SCALE);
        #pragma unroll
        for (int o = 0; o < COUT; ++o)
            coef[i * COUT + o + (size_t)b * CINN * COUT] = t * conv_w[i * COUT + o];
    }
}

// ---------------------------------------------------------------------------
// Kernel 2: y[b,p,o] = sum_i x[b,p,i]*coef[b,i,o]; out = leaky(y+bias)
// 8 lanes per pixel; lane l8 owns channels {4*l8 + 32*j + k : j,k in 0..3}.
// Coalesced: per pixel the 8 lanes' float4 loads cover 512B contiguous.
// grid: (GRID_X, B), block: 256
// R6 single-variable probe: #pragma unroll 4 -> 2 (halve in-flight load
// destination VGPRs; test the 128-VGPR occupancy-step theory).
// ---------------------------------------------------------------------------
__global__ __launch_bounds__(256)
void modconv_kernel(const float* __restrict__ x,
                    const float* __restrict__ coef,
                    const float* __restrict__ bias,
                    float* __restrict__ out) {
    const int b   = blockIdx.y;
    const int l8  = threadIdx.x & 7;                       // lane in 8-group
    const int gid = (blockIdx.x * 256 + threadIdx.x) >> 3; // group id in batch

    // per-lane coefficients: c[j][k][o] for channel 4*l8 + 32*j + k
    float c[4][4][3];
    const float* cp = coef + (size_t)b * CINN * COUT;
    #pragma unroll
    for (int j = 0; j < 4; ++j)
        #pragma unroll
        for (int k = 0; k < 4; ++k) {
            const int ch = 4 * l8 + 32 * j + k;
            #pragma unroll
            for (int o = 0; o < COUT; ++o)
                c[j][k][o] = cp[ch * COUT + o];
        }

    const int r = l8 & 3;                       // output index this lane writes
    const float bb = bias[r < 3 ? r : 0];

    const float4* xb = (const float4*)(x + (size_t)b * PIX * CINN);
    float*        ob = out + (size_t)b * PIX * COUT;

    #pragma unroll 2
    for (int t = 0; t < ITERS; ++t) {
        const int p = t * NGROUPS + gid;        // pixel index within batch
        const float4* xp = xb + (size_t)p * (CINN / 4);

        float a0 = 0.f, a1 = 0.f, a2 = 0.f;
        #pragma unroll
        for (int j = 0; j < 4; ++j) {
            const float4 v = xp[l8 + 8 * j];
            a0 += v.x * c[j][0][0] + v.y * c[j][1][0] + v.z * c[j][2][0] + v.w * c[j][3][0];
            a1 += v.x * c[j][0][1] + v.y * c[j][1][1] + v.z * c[j][2][1] + v.w * c[j][3][1];
            a2 += v.x * c[j][0][2] + v.y * c[j][1][2] + v.z * c[j][2][2] + v.w * c[j][3][2];
        }

        // reduce over the 8-lane group:
        a0 += __shfl_xor(a0, 1); a1 += __shfl_xor(a1, 1); a2 += __shfl_xor(a2, 1);
        a0 += __shfl_xor(a0, 2); a1 += __shfl_xor(a1, 2); a2 += __shfl_xor(a2, 2);
        float v = (r == 0) ? a0 : ((r == 1) ? a1 : a2);
        v += __shfl_xor(v, 4);

        if (l8 < 3) {   // lanes 0..2 of the group write outputs 0..2
            const float y = v + bb;
            ob[(size_t)p * COUT + r] = (y > 0.f) ? y : LRELU_SLOPE * y;
        }
    }
}

// ---------------------------------------------------------------------------
extern "C" void kernel_launch(void* const* d_in, const int* in_sizes, int n_in,
                              void* d_out, int out_size, void* d_ws, size_t ws_size,
                              hipStream_t stream) {
    const float* x      = (const float*)d_in[0];
    const float* w      = (const float*)d_in[1];
    const float* fc_w   = (const float*)d_in[2];
    const float* fc_b   = (const float*)d_in[3];
    const float* conv_w = (const float*)d_in[4];
    const float* bias   = (const float*)d_in[5];
    float*       out    = (float*)d_out;
    float*       coef   = (float*)d_ws;   // B*CIN*COUT = 3072 floats = 12 KB

    style_kernel<<<dim3(BB, 8), dim3(256), 0, stream>>>(w, fc_w, fc_b, conv_w, coef);

    modconv_kernel<<<dim3(GRID_X, BB), dim3(256), 0, stream>>>(x, coef, bias, out);
}

// Round 7
// 49.861 us; speedup vs baseline: 1.0203x; 1.0203x over previous
//
#include <hip/hip_runtime.h>
#include <math.h>

// Problem constants (match reference)
#define BB   8
#define HH   256
#define WW   256
#define CINN 128
#define WDIM 512
#define COUT 3

constexpr float LRELU_SLOPE = 0.2f;
constexpr float ACT_GAIN    = 1.4142135623730951f;   // sqrt(2)
constexpr float FC_SCALE    = 0.04419417382415922f;  // 1/sqrt(512)
constexpr float CONV_SCALE  = 0.08838834764831843f;  // 1/sqrt(128)

constexpr int PIX = HH * WW;                 // 65536 pixels per batch
constexpr int GRID_X = 256;                  // blocks per batch for kernel 2
constexpr int GROUPS_PER_BLK = 256 / 8;      // 32 groups of 8 lanes
constexpr int NGROUPS = GRID_X * GROUPS_PER_BLK;  // 8192 groups per batch
constexpr int ITERS = PIX / NGROUPS;         // 8 pixels per group

// ---------------------------------------------------------------------------
// Kernel 1: style FC + fold into coef[b][i][o].
// grid (B, 8): block owns batch b, channels cg*16..cg*16+15.
// block 256 = 16 channels x 16 k-slices of 32. LDS reduce.
// ---------------------------------------------------------------------------
__global__ __launch_bounds__(256)
void style_kernel(const float* __restrict__ w,
                  const float* __restrict__ fc_w,
                  const float* __restrict__ fc_b,
                  const float* __restrict__ conv_w,
                  float* __restrict__ coef) {
    __shared__ float wrow[WDIM];
    __shared__ float part[16][16];

    const int b  = blockIdx.x;
    const int c0 = blockIdx.y * 16;            // first channel of this block
    const int c  = threadIdx.x & 15;           // channel within group
    const int s  = threadIdx.x >> 4;           // k-slice 0..15

    // stage w[b,:] into LDS (coalesced, 2 per thread)
    wrow[threadIdx.x]       = w[b * WDIM + threadIdx.x];
    wrow[threadIdx.x + 256] = w[b * WDIM + threadIdx.x + 256];
    __syncthreads();

    const float* fcol = fc_w + (size_t)(s * 32) * CINN + (c0 + c);
    const float* wk   = wrow + s * 32;

    float acc = 0.f;
    #pragma unroll
    for (int k = 0; k < 32; ++k)
        acc = fmaf(wk[k], fcol[(size_t)k * CINN], acc);

    part[s][c] = acc;
    __syncthreads();

    if (threadIdx.x < 16) {                    // thread c finalizes channel c0+c
        float t = 0.f;
        #pragma unroll
        for (int r = 0; r < 16; ++r) t += part[r][threadIdx.x];
        const int i = c0 + threadIdx.x;
        t = t * FC_SCALE + fc_b[i];
        t = (t > 0.f ? t : LRELU_SLOPE * t) * (ACT_GAIN * CONV_SCALE);
        #pragma unroll
        for (int o = 0; o < COUT; ++o)
            coef[i * COUT + o + (size_t)b * CINN * COUT] = t * conv_w[i * COUT + o];
    }
}

// ---------------------------------------------------------------------------
// Kernel 2: y[b,p,o] = sum_i x[b,p,i]*coef[b,i,o]; out = leaky(y+bias)
// 8 lanes per pixel; lane l8 owns channels {4*l8 + 32*j + k : j,k in 0..3}.
// Coalesced: per pixel the 8 lanes' float4 loads cover 512B contiguous.
// grid: (GRID_X, B), block: 256
// R7 single-variable probe: full unroll (8) of the t-loop — max loads in
// flight per lane. Tests MLP-bound vs at-ceiling vs VGPR-cliff.
// ---------------------------------------------------------------------------
__global__ __launch_bounds__(256)
void modconv_kernel(const float* __restrict__ x,
                    const float* __restrict__ coef,
                    const float* __restrict__ bias,
                    float* __restrict__ out) {
    const int b   = blockIdx.y;
    const int l8  = threadIdx.x & 7;                       // lane in 8-group
    const int gid = (blockIdx.x * 256 + threadIdx.x) >> 3; // group id in batch

    // per-lane coefficients: c[j][k][o] for channel 4*l8 + 32*j + k
    float c[4][4][3];
    const float* cp = coef + (size_t)b * CINN * COUT;
    #pragma unroll
    for (int j = 0; j < 4; ++j)
        #pragma unroll
        for (int k = 0; k < 4; ++k) {
            const int ch = 4 * l8 + 32 * j + k;
            #pragma unroll
            for (int o = 0; o < COUT; ++o)
                c[j][k][o] = cp[ch * COUT + o];
        }

    const int r = l8 & 3;                       // output index this lane writes
    const float bb = bias[r < 3 ? r : 0];

    const float4* xb = (const float4*)(x + (size_t)b * PIX * CINN);
    float*        ob = out + (size_t)b * PIX * COUT;

    #pragma unroll 8
    for (int t = 0; t < ITERS; ++t) {
        const int p = t * NGROUPS + gid;        // pixel index within batch
        const float4* xp = xb + (size_t)p * (CINN / 4);

        float a0 = 0.f, a1 = 0.f, a2 = 0.f;
        #pragma unroll
        for (int j = 0; j < 4; ++j) {
            const float4 v = xp[l8 + 8 * j];
            a0 += v.x * c[j][0][0] + v.y * c[j][1][0] + v.z * c[j][2][0] + v.w * c[j][3][0];
            a1 += v.x * c[j][0][1] + v.y * c[j][1][1] + v.z * c[j][2][1] + v.w * c[j][3][1];
            a2 += v.x * c[j][0][2] + v.y * c[j][1][2] + v.z * c[j][2][2] + v.w * c[j][3][2];
        }

        // reduce over the 8-lane group:
        a0 += __shfl_xor(a0, 1); a1 += __shfl_xor(a1, 1); a2 += __shfl_xor(a2, 1);
        a0 += __shfl_xor(a0, 2); a1 += __shfl_xor(a1, 2); a2 += __shfl_xor(a2, 2);
        float v = (r == 0) ? a0 : ((r == 1) ? a1 : a2);
        v += __shfl_xor(v, 4);

        if (l8 < 3) {   // lanes 0..2 of the group write outputs 0..2
            const float y = v + bb;
            ob[(size_t)p * COUT + r] = (y > 0.f) ? y : LRELU_SLOPE * y;
        }
    }
}

// ---------------------------------------------------------------------------
extern "C" void kernel_launch(void* const* d_in, const int* in_sizes, int n_in,
                              void* d_out, int out_size, void* d_ws, size_t ws_size,
                              hipStream_t stream) {
    const float* x      = (const float*)d_in[0];
    const float* w      = (const float*)d_in[1];
    const float* fc_w   = (const float*)d_in[2];
    const float* fc_b   = (const float*)d_in[3];
    const float* conv_w = (const float*)d_in[4];
    const float* bias   = (const float*)d_in[5];
    float*       out    = (float*)d_out;
    float*       coef   = (float*)d_ws;   // B*CIN*COUT = 3072 floats = 12 KB

    style_kernel<<<dim3(BB, 8), dim3(256), 0, stream>>>(w, fc_w, fc_b, conv_w, coef);

    modconv_kernel<<<dim3(GRID_X, BB), dim3(256), 0, stream>>>(x, coef, bias, out);
}